// Round 20
// baseline (140.952 us; speedup 1.0000x reference)
//
#include <hip/hip_runtime.h>
#include <hip/hip_bf16.h>

// B=8, L=512, D=1024, H=16, HD=64
#define BB 8
#define LL 512
#define DD 1024
#define HH 16
#define HD 64
#define LOG2E 1.4426950408889634f

typedef __attribute__((ext_vector_type(8))) unsigned short u16x8;
typedef __attribute__((ext_vector_type(4))) unsigned short u16x4;
typedef __attribute__((ext_vector_type(8))) __bf16 bf16x8;
typedef __attribute__((ext_vector_type(4))) float f32x4;
typedef __attribute__((ext_vector_type(16))) float f32x16;

#define DEV __device__ __forceinline__

DEV unsigned short f2bf(float f) {               // native v_cvt (RNE)
    return __builtin_bit_cast(unsigned short, (__bf16)f);
}
DEV f32x4 mfma16(u16x8 a, u16x8 b, f32x4 c) {
    return __builtin_amdgcn_mfma_f32_16x16x32_bf16(
        __builtin_bit_cast(bf16x8, a), __builtin_bit_cast(bf16x8, b), c, 0, 0, 0);
}
DEV f32x16 mfma32(u16x8 a, u16x8 b, f32x16 c) {
    return __builtin_amdgcn_mfma_f32_32x32x16_bf16(
        __builtin_bit_cast(bf16x8, a), __builtin_bit_cast(bf16x8, b), c, 0, 0, 0);
}
// async global->LDS, 16B per lane; LDS dest = wave-uniform base + lane*16
typedef __attribute__((address_space(1))) void gv_t;
typedef __attribute__((address_space(3))) void lv_t;
DEV void gload16(const void* g, void* l) {
    __builtin_amdgcn_global_load_lds((gv_t*)g, (lv_t*)l, 16, 0, 0);
}

// Frag-major layouts (so every attn load is base + lane*16B, coalesced):
//  Q/K:  X[bh][tile=i>>5][ks=hd>>4][l=hi*32+lq][j]  elem = T[i][hd]
//  QP/KP: same but outer index h
//  V:    V[bh][tile][c=dblk*2+ps][l][j]             elem = V[i][hd]

// --------------------------- fused prep: cvt_x | transpose(wqkv) |
// transpose(wfc) | posg, dispatched by block range (saves 3 kernel gaps)
__global__ __launch_bounds__(256) void prep(
    const float* __restrict__ x, unsigned short* __restrict__ xb,
    const float* __restrict__ w_qkv, unsigned short* __restrict__ wqt,
    const float* __restrict__ w_fc, unsigned short* __restrict__ wft,
    const float* __restrict__ w_qkp, unsigned short* __restrict__ qpx,
    unsigned short* __restrict__ kpx) {
    __shared__ __align__(16) char lds[24576];
    int blk = blockIdx.x;
    int t = threadIdx.x;
    if (blk < 4096) {
        int i = blk * 256 + t;
        f32x4 v = *(const f32x4*)(x + i * 4);
        u16x4 o;
        o[0] = f2bf(v[0]); o[1] = f2bf(v[1]);
        o[2] = f2bf(v[2]); o[3] = f2bf(v[3]);
        *(u16x4*)(xb + i * 4) = o;
    } else if (blk < 7168) {
        int r = blk - 4096;
        int c0 = (r % 96) * 32, r0 = (r / 96) * 32;
        auto tile = (unsigned short(*)[33])lds;
        int tx = t & 31, ty = t >> 5;
#pragma unroll
        for (int i = 0; i < 32; i += 8)
            tile[ty + i][tx] = f2bf(w_qkv[(r0 + ty + i) * 3072 + c0 + tx]);
        __syncthreads();
#pragma unroll
        for (int i = 0; i < 32; i += 8)
            wqt[(c0 + ty + i) * 1024 + r0 + tx] = tile[tx][ty + i];
    } else if (blk < 8192) {
        int r = blk - 7168;
        int c0 = (r % 32) * 32, r0 = (r / 32) * 32;
        auto tile = (unsigned short(*)[33])lds;
        int tx = t & 31, ty = t >> 5;
#pragma unroll
        for (int i = 0; i < 32; i += 8)
            tile[ty + i][tx] = f2bf(w_fc[(r0 + ty + i) * 1024 + c0 + tx]);
        __syncthreads();
#pragma unroll
        for (int i = 0; i < 32; i += 8)
            wft[(c0 + ty + i) * 1024 + r0 + tx] = tile[tx][ty + i];
    } else {
        int r = blk - 8192;
        int c0 = (r % 64) * 32, i0 = (r / 64) * 64;
        auto peS = (float(*)[64])lds;
        auto wS = (float(*)[32])(lds + 16384);
#pragma unroll
        for (int j = 0; j < 16; ++j) {
            int o = t + j * 256;
            int ri = o >> 6, d = o & 63, dd = d & 31;
            float inv = expf((float)dd * -0.2971077539347156f);
            float ang = (float)(i0 + ri - 256) * inv;
            peS[ri][d] = (d < 32) ? sinf(ang) : cosf(ang);
        }
#pragma unroll
        for (int j = 0; j < 8; ++j) {
            int o = t + j * 256;
            wS[o >> 5][o & 31] = w_qkp[(o >> 5) * 2048 + c0 + (o & 31)];
        }
        __syncthreads();
#pragma unroll
        for (int j = 0; j < 8; ++j) {
            int o = t + j * 256;
            int row = o >> 5, col = o & 31;
            float acc = 0.0f;
#pragma unroll
            for (int k = 0; k < 64; ++k) acc += peS[row][k] * wS[k][col];
            int c = c0 + col, i = i0 + row;
            int qt = i >> 5, lq = i & 31;
            int cc = (c < 1024) ? c : (c - 1024);
            int h = cc >> 6, kk = cc & 63;
            int ks = kk >> 4, h2 = (kk >> 3) & 1, jj = kk & 7;
            unsigned idx = ((unsigned)(h * 4096 + qt * 256 + ks * 64 +
                            h2 * 32 + lq) << 3) + jj;
            if (c < 1024) qpx[idx] = f2bf(acc * LOG2E);
            else          kpx[idx] = f2bf(acc);
        }
    }
}

// ------------------------------------------- 8-phase 256x256 GEMM (QKV)
// M=4096 N=3072 K=1024. BM=BN=256 BK=64, 512 thr / 8 waves (2Mx4N), LDS
// 128KB = [2 dbuf][2 half][128][64] x {A,B}. Per K-tile 4 phases
// (k0n0,k0n1,k1n0,k1n1) x 16 MFMA; 8 phases/iter = 2 K-tiles. Each phase
// stages one half-tile whose last ds_read completed >=1 barrier earlier
// (proof in session notes); counted vmcnt(2) only at phases 4/8. Swizzle:
// LDS[row][c] holds global chunk c^(row&7) via pre-swizzled gload SOURCE
// (dest linear, rule 21) + XOR on ds_read -> 2-way banks. setprio around
// MFMA clusters (T5; pays only on 8-phase). Epilogue: frag-major scatter.
__global__ __launch_bounds__(512, 2) void gemm8p(
    const unsigned short* __restrict__ A, const unsigned short* __restrict__ Bt,
    unsigned short* __restrict__ o0, unsigned short* __restrict__ o1,
    unsigned short* __restrict__ o2) {
    __shared__ __align__(16) unsigned short As[2][2][8192];   // 64KB
    __shared__ __align__(16) unsigned short Bs[2][2][8192];   // 64KB
    const int K = 1024;
    int g = blockIdx.x;                       // 192 blocks
    int swz = (g & 7) * 24 + (g >> 3);        // XCD-bijective (192 = 8*24)
    int bx = swz % 12, by = swz / 12;
    int m0 = by * 256, n0 = bx * 256;
    int t = threadIdx.x;
    int w = t >> 6, l = t & 63, lg = (l >> 4) & 3, lc = l & 15;
    int wr = w >> 2, wcn = w & 3;             // wave row-half / col-quarter
    int rsw = lc & 7;                         // read-side f(row)=row&7

    // per-lane pre-swizzled global base: row w*8+(l>>3), chunk (l&7)^(l>>3)
    const unsigned short* Abase =
        A + (m0 + w * 8 + (l >> 3)) * K + (((l & 7) ^ ((l >> 3) & 7)) << 3);
    const unsigned short* Bbase =
        Bt + (n0 + w * 8 + (l >> 3)) * K + (((l & 7) ^ ((l >> 3) & 7)) << 3);

    auto stA = [&](int db, int half, int tile) {
        gload16(Abase + (half * 128) * K + tile * 64, &As[db][half][w * 512]);
        gload16(Abase + (half * 128 + 64) * K + tile * 64,
                &As[db][half][4096 + w * 512]);
    };
    auto stB = [&](int db, int half, int tile) {
        gload16(Bbase + (half * 128) * K + tile * 64, &Bs[db][half][w * 512]);
        gload16(Bbase + (half * 128 + 64) * K + tile * 64,
                &Bs[db][half][4096 + w * 512]);
    };

    f32x4 acc[8][4] = {};
    u16x8 af[8], bf[2];

    // prologue: tile0 all 4 halves + tile1 A-h0 (10 loads)
    stA(0, 0, 0); stA(0, 1, 0); stB(0, 0, 0); stB(0, 1, 0); stA(1, 0, 1);
    asm volatile("s_waitcnt vmcnt(2)" ::: "memory");
    __builtin_amdgcn_s_barrier();

#pragma unroll
    for (int i = 0; i < 8; ++i) {
#pragma unroll
        for (int half = 0; half < 2; ++half) {
            const int db = half;
            const int tile = 2 * i + half;
            (void)tile;
#pragma unroll
            for (int pp = 0; pp < 4; ++pp) {
                const int ks = pp >> 1;       // k-step 0/1
                const int nh = pp & 1;        // n-half 0/1
                // ---- ds-reads for this phase
                if (nh == 0) {                // fresh A k-step
#pragma unroll
                    for (int mf = 0; mf < 8; ++mf)
                        af[mf] = *(const u16x8*)&As[db][wr]
                            [(mf * 16 + lc) * 64 + (((ks * 4 + lg) ^ rsw) << 3)];
                }
#pragma unroll
                for (int nf = 0; nf < 2; ++nf)
                    bf[nf] = *(const u16x8*)&Bs[db][wcn >> 1]
                        [((wcn & 1) * 64 + (nh * 2 + nf) * 16 + lc) * 64 +
                         (((ks * 4 + lg) ^ rsw) << 3)];
                // ---- stage one half-tile (stream schedule; see header)
                if (half == 0) {
                    if (pp == 0) stA(1, 1, 2 * i + 1);
                    else if (pp == 1) stB(1, 0, 2 * i + 1);
                    else if (pp == 2) stB(1, 1, 2 * i + 1);
                    else if (i < 7) stA(0, 0, 2 * i + 2);
                } else {
                    if (i < 7) {
                        if (pp == 0) stA(0, 1, 2 * i + 2);
                        else if (pp == 1) stB(0, 0, 2 * i + 2);
                        else if (pp == 2) stB(0, 1, 2 * i + 2);
                        else stA(1, 0, 2 * i + 3);
                    }
                }
                // ---- counted vmcnt only at phases 4 and 8 (pp==3)
                if (pp == 3) {
                    if (half == 0) {
                        if (i < 7)
                            asm volatile("s_waitcnt vmcnt(2)" ::: "memory");
                        else
                            asm volatile("s_waitcnt vmcnt(0)" ::: "memory");
                    } else if (i < 7) {
                        asm volatile("s_waitcnt vmcnt(2)" ::: "memory");
                    }
                }
                __builtin_amdgcn_s_barrier();
                asm volatile("s_waitcnt lgkmcnt(0)" ::: "memory");
                __builtin_amdgcn_sched_barrier(0);
                __builtin_amdgcn_s_setprio(1);
#pragma unroll
                for (int mf = 0; mf < 8; ++mf)
#pragma unroll
                    for (int nf = 0; nf < 2; ++nf)
                        acc[mf][nh * 2 + nf] =
                            mfma16(af[mf], bf[nf], acc[mf][nh * 2 + nf]);
                __builtin_amdgcn_s_setprio(0);
                __builtin_amdgcn_s_barrier();
            }
        }
    }

    // ---- epilogue: frag-major scatter (q *log2e, k, v)
#pragma unroll
    for (int mf = 0; mf < 8; ++mf)
#pragma unroll
        for (int nf = 0; nf < 4; ++nf)
#pragma unroll
            for (int r = 0; r < 4; ++r) {
                int row = m0 + wr * 128 + mf * 16 + lg * 4 + r;
                int col = n0 + wcn * 64 + nf * 16 + lc;
                float v = acc[mf][nf][r];
                int bb = row >> 9, i = row & 511;
                int which = col >> 10, dd = col & 1023;
                int hh = dd >> 6, hd = dd & 63;
                int bh2 = bb * HH + hh;
                int tl = i >> 5, io = i & 31;
                if (which == 2) {             // V frag-major
                    int h2 = (io >> 2) & 1, ps = (io >> 4) & 1;
                    int j = (io & 3) | (((io >> 3) & 1) << 2);
                    int dblk = hd >> 5, lq = hd & 31;
                    unsigned idx = ((unsigned)(bh2 * 4096 + tl * 256 +
                                    (dblk * 2 + ps) * 64 + h2 * 32 + lq)
                                    << 3) + j;
                    o2[idx] = f2bf(v);
                } else {                      // Q/K frag-major
                    int ks = hd >> 4, h2 = (hd >> 3) & 1, j = hd & 7;
                    unsigned idx = ((unsigned)(bh2 * 4096 + tl * 256 +
                                    ks * 64 + h2 * 32 + io) << 3) + j;
                    if (which == 0) o0[idx] = f2bf(v * LOG2E);
                    else            o1[idx] = f2bf(v);
                }
            }
}

// ---------------------------------------------------------------- GEMM (FC)
// 2-phase proven structure: 128x128 tile, BK=32, 512 thr / 8 waves,
// triple-buffered LDS + counted vmcnt + raw barriers. fp32 out + bias.
__global__ __launch_bounds__(512) void gemm_fc(
    const unsigned short* __restrict__ A, const unsigned short* __restrict__ Bt,
    int M, int N, int K, int NBX, float* __restrict__ fout,
    const float* __restrict__ bias) {
    __shared__ __align__(16) unsigned short As[3][128 * 32];
    __shared__ __align__(16) unsigned short Bs[3][128 * 32];
    int g = blockIdx.x;
    int swz = (g & 7) * (gridDim.x >> 3) + (g >> 3);
    int bx = swz % NBX, by = swz / NBX;
    int m0 = by * 128, n0 = bx * 128;
    int t = threadIdx.x;
    int w = t >> 6, l = t & 63, lg = l >> 4, lc = l & 15;
    int rh = w >> 2, cq = w & 3;

    f32x4 acc[4][2] = {};

    int sr = t >> 2;
    int sc = (t & 3) ^ ((t >> 3) & 3);
    const unsigned short* Ab = A + (m0 + sr) * K + sc * 8;
    const unsigned short* Bb = Bt + (n0 + sr) * K + sc * 8;
    int rsw = (lc >> 1) & 3;

    auto stage = [&](int buf, int k0) {
        gload16(Ab + k0, &As[buf][w * 512]);
        gload16(Bb + k0, &Bs[buf][w * 512]);
    };

    stage(0, 0);
    stage(1, 32);
    stage(2, 64);
    int cur = 0;
    for (int k0 = 0; k0 < K; k0 += 32) {
        int rem = (K - k0) >> 5;
        if (rem > 2)
            asm volatile("s_waitcnt vmcnt(4)" ::: "memory");
        else if (rem == 2)
            asm volatile("s_waitcnt vmcnt(2)" ::: "memory");
        else
            asm volatile("s_waitcnt vmcnt(0)" ::: "memory");
        __builtin_amdgcn_sched_barrier(0);
        __builtin_amdgcn_s_barrier();
        __builtin_amdgcn_sched_barrier(0);
        u16x8 af[4], bf[2];
#pragma unroll
        for (int mm = 0; mm < 4; ++mm)
            af[mm] = *(const u16x8*)&As[cur][(rh * 64 + mm * 16 + lc) * 32 +
                                             ((lg ^ rsw) << 3)];
#pragma unroll
        for (int nn = 0; nn < 2; ++nn)
            bf[nn] = *(const u16x8*)&Bs[cur][(cq * 32 + nn * 16 + lc) * 32 +
                                             ((lg ^ rsw) << 3)];
        asm volatile("s_waitcnt lgkmcnt(0)" ::: "memory");
        __builtin_amdgcn_sched_barrier(0);
        __builtin_amdgcn_s_barrier();
        __builtin_amdgcn_sched_barrier(0);
        if (k0 + 96 < K) stage(cur, k0 + 96);
#pragma unroll
        for (int mm = 0; mm < 4; ++mm)
#pragma unroll
            for (int nn = 0; nn < 2; ++nn)
                acc[mm][nn] = mfma16(af[mm], bf[nn], acc[mm][nn]);
        cur = (cur == 2) ? 0 : cur + 1;
    }

#pragma unroll
    for (int mm = 0; mm < 4; ++mm)
#pragma unroll
        for (int nn = 0; nn < 2; ++nn)
#pragma unroll
            for (int r = 0; r < 4; ++r) {
                int row = m0 + rh * 64 + mm * 16 + lg * 4 + r;
                int col = n0 + cq * 32 + nn * 16 + lc;
                fout[row * N + col] = acc[mm][nn][r] + bias[col];
            }
}

// ---------------------------------------------------------------- attention
// Swapped-QK^T + 2-way key split, frag-major inputs, TWO q-chunks per wave.
// block = 128 threads / 2 waves; __launch_bounds__(128,1) keeps the 512-VGPR
// cap (default heuristic caps at 64 VGPR and spills the ~200-reg state).
__global__ __launch_bounds__(128, 1) void attn_k(
    const unsigned short* __restrict__ Qx, const unsigned short* __restrict__ Kx,
    const unsigned short* __restrict__ Vx, const unsigned short* __restrict__ QPx,
    const unsigned short* __restrict__ KPx, const int* __restrict__ mask,
    const int* __restrict__ qmask, const float* __restrict__ shp,
    unsigned short* __restrict__ out) {
    __shared__ float mbuf[2][64];
    __shared__ float lsbuf[2][64];
    __shared__ float obuf[2][64][33];          // +1 pad: conflict-free

    int g = blockIdx.x;                        // 1024 blocks
    int bid = ((g & 7) << 7) + (g >> 3);       // one batch per XCD
    int b = bid >> 7, h = (bid >> 3) & 15, qp = bid & 7;
    int t = threadIdx.x, kh = t >> 6, l = t & 63;
    int lq = l & 31, hi = l >> 5;
    int c0 = qp * 2;                           // this block's two q-chunks
    int qA = c0 * 32 + lq, qB = qA + 32;
    int bh = b * HH + h;

    const unsigned short* qbA  = Qx  + (((unsigned)(bh * 4096 + c0 * 256)) << 3) + (l << 3);
    const unsigned short* qpbA = QPx + (((unsigned)(h  * 4096 + c0 * 256)) << 3) + (l << 3);
    u16x8 qfA[4], pfA[4], qfB[4], pfB[4];
#pragma unroll
    for (int ks = 0; ks < 4; ++ks) {
        qfA[ks] = *(const u16x8*)(qbA + ks * 512);
        pfA[ks] = *(const u16x8*)(qpbA + ks * 512);
        qfB[ks] = *(const u16x8*)(qbA + 2048 + ks * 512);
        pfB[ks] = *(const u16x8*)(qpbA + 2048 + ks * 512);
    }

    unsigned long long km[4], qm[4];
#pragma unroll
    for (int t8 = 0; t8 < 4; ++t8) {
        int base = b * LL + (kh * 4 + t8) * 64 + l;
        km[t8] = __ballot(mask[base] != 0);
        qm[t8] = __ballot(qmask[base] != 0);
    }
    int qiA = (qmask[b * LL + qA] != 0) ? 1 : 0;
    int qiB = (qmask[b * LL + qB] != 0) ? 1 : 0;

    const float M0 = -1.0e30f, NEGF = -3.0e38f, THR = 8.0f;
    float negs = -(*shp) * LOG2E;
    float mA = M0, lsA = 0.0f, mB = M0, lsB = 0.0f;
    f32x16 oA0 = {}, oA1 = {}, oB0 = {}, oB1 = {};
    float fqA = (float)(qA - 4 * hi);
    float fqB = (float)(qB - 4 * hi);

#pragma unroll
    for (int tt = 0; tt < 8; ++tt) {
        int ttg = kh * 8 + tt;
        const unsigned short* kb  = Kx  + (((unsigned)(bh * 4096 + ttg * 256)) << 3) + (l << 3);
        const unsigned short* kpb = KPx + (((unsigned)(h  * 4096 + ttg * 256)) << 3) + (l << 3);
        const unsigned short* vb  = Vx  + (((unsigned)(bh * 4096 + ttg * 256)) << 3) + (l << 3);
        u16x8 kf[4], kpf[4], vf[4];
#pragma unroll
        for (int ks = 0; ks < 4; ++ks) {
            kf[ks]  = *(const u16x8*)(kb + ks * 512);
            kpf[ks] = *(const u16x8*)(kpb + ks * 512);
            vf[ks]  = *(const u16x8*)(vb + ks * 512);
        }
        f32x16 sA = {}, sB = {};
#pragma unroll
        for (int ks = 0; ks < 4; ++ks) {
            sA = mfma32(kf[ks], qfA[ks], sA);
            sB = mfma32(kf[ks], qfB[ks], sB);
        }
#pragma unroll
        for (int ks = 0; ks < 4; ++ks) {
            sA = mfma32(kpf[ks], pfA[ks], sA);
            sB = mfma32(kpf[ks], pfB[ks], sB);
        }

        unsigned kwn = ((unsigned)(km[tt >> 1] >> ((tt & 1) * 32))) >> (hi * 4);
        unsigned qwn = ((unsigned)(qm[tt >> 1] >> ((tt & 1) * 32))) >> (hi * 4);
        float btA = fqA - 32.0f * (float)ttg;
        float btB = fqB - 32.0f * (float)ttg;

        {   // chunk A
            float p[16];
#pragma unroll
            for (int r = 0; r < 16; ++r) {
                const int off = (r & 3) + 8 * (r >> 2);
                float v = sA[r];
                v = (((qwn >> off) & 1u) == (unsigned)qiA) ? v : 0.0f;
                float dr = btA - (float)off;
                v = __builtin_fmaf(negs * dr, dr, v);
                v = ((kwn >> off) & 1u) ? v : NEGF;
                p[r] = v;
            }
            float a0 = fmaxf(fmaxf(p[0], p[1]), fmaxf(p[2], p[3]));
            float a1 = fmaxf(fmaxf(p[4], p[5]), fmaxf(p[6], p[7]));
            float a2 = fmaxf(fmaxf(p[8], p[9]), fmaxf(p[10], p[11]));
            float a3 = fmaxf(fmaxf(p[12], p[13]), fmaxf(p[14], p[15]));
            float pmax = fmaxf(fmaxf(a0, a1), fmaxf(a2, a3));
            pmax = fmaxf(pmax, __shfl_xor(pmax, 32));
            if (!__all(pmax <= mA + THR)) {
                float mn = fmaxf(mA, pmax);
                float sc = __builtin_amdgcn_exp2f(mA - mn);
#pragma unroll
                for (int r = 0; r < 16; ++r) { oA0[r] *= sc; oA1[r] *= sc; }
                lsA *= sc;
                mA = mn;
            }
#pragma unroll
            for (int r = 0; r < 16; ++r) p[r] = __builtin_amdgcn_exp2f(p[r] - mA);
            lsA += (((p[0] + p[1]) + (p[2] + p[3])) + ((p[4] + p[5]) + (p[6] + p[7]))) +
                   (((p[8] + p[9]) + (p[10] + p[11])) +
                    ((p[12] + p[13]) + (p[14] + p[15])));
            u16x8 pf0, pf1;
#pragma unroll
            for (int j = 0; j < 8; ++j) { pf0[j] = f2bf(p[j]); pf1[j] = f2bf(p[8 + j]); }
            oA0 = mfma32(vf[0], pf0, oA0);
            oA0 = mfma32(vf[1], pf1, oA0);
            oA1 = mfma32(vf[2], pf0, oA1);
            oA1 = mfma32(vf[3], pf1, oA1);
        }
        {   // chunk B
            float p[16];
#pragma unroll
            for (int r = 0; r < 16; ++r) {
                const int off = (r & 3) + 8 * (r >> 2);
                float v = sB[r];
                v = (((qwn >> off) & 1u) == (unsigned)qiB) ? v : 0.0f;
                float dr = btB - (float)off;
                v = __builtin_fmaf(negs * dr, dr, v);
                v = ((kwn >> off) & 1u) ? v : NEGF;
                p[r] = v;
            }
            float a0 = fmaxf(fmaxf(p[0], p[1]), fmaxf(p[2], p[3]));
            float a1 = fmaxf(fmaxf(p[4], p[5]), fmaxf(p[6], p[7]));
            float a2 = fmaxf(fmaxf(p[8], p[9]), fmaxf(p[10], p[11]));
            float a3 = fmaxf(fmaxf(p[12], p[13]), fmaxf(p[14], p[15]));
            float pmax = fmaxf(fmaxf(a0, a1), fmaxf(a2, a3));
            pmax = fmaxf(pmax, __shfl_xor(pmax, 32));
            if (!__all(pmax <= mB + THR)) {
                float mn = fmaxf(mB, pmax);
                float sc = __builtin_amdgcn_exp2f(mB - mn);
#pragma unroll
                for (int r = 0; r < 16; ++r) { oB0[r] *= sc; oB1[r] *= sc; }
                lsB *= sc;
                mB = mn;
            }
#pragma unroll
            for (int r = 0; r < 16; ++r) p[r] = __builtin_amdgcn_exp2f(p[r] - mB);
            lsB += (((p[0] + p[1]) + (p[2] + p[3])) + ((p[4] + p[5]) + (p[6] + p[7]))) +
                   (((p[8] + p[9]) + (p[10] + p[11])) +
                    ((p[12] + p[13]) + (p[14] + p[15])));
            u16x8 pf0, pf1;
#pragma unroll
            for (int j = 0; j < 8; ++j) { pf0[j] = f2bf(p[j]); pf1[j] = f2bf(p[8 + j]); }
            oB0 = mfma32(vf[0], pf0, oB0);
            oB0 = mfma32(vf[1], pf1, oB0);
            oB1 = mfma32(vf[2], pf0, oB1);
            oB1 = mfma32(vf[3], pf1, oB1);
        }
    }

    if (kh == 1) {
        mbuf[0][l] = mA;  lsbuf[0][l] = lsA;
        mbuf[1][l] = mB;  lsbuf[1][l] = lsB;
#pragma unroll
        for (int r = 0; r < 16; ++r) {
            obuf[0][l][r] = oA0[r];
            obuf[0][l][16 + r] = oA1[r];
            obuf[1][l][r] = oB0[r];
            obuf[1][l][16 + r] = oB1[r];
        }
    }
    __syncthreads();
    if (kh == 0) {
        {   // chunk A
            float m1 = mbuf[0][l], ls1 = lsbuf[0][l];
            float mm = fmaxf(mA, m1);
            float sc0 = __builtin_amdgcn_exp2f(mA - mm);
            float sc1 = __builtin_amdgcn_exp2f(m1 - mm);
            float lsm = lsA * sc0 + ls1 * sc1;
            float rs = lsm + __shfl_xor(lsm, 32);
            float rinv = __builtin_amdgcn_rcpf(rs);
            unsigned short* ob = out + ((long)(b * LL + qA)) * DD + h * HD + hi * 4;
#pragma unroll
            for (int rg = 0; rg < 4; ++rg) {
                u16x4 pk0, pk1;
#pragma unroll
                for (int rr = 0; rr < 4; ++rr) {
                    int i = rg * 4 + rr;
                    float v0 = __builtin_fmaf(oA0[i], sc0, obuf[0][l][i] * sc1);
                    float v1 = __builtin_fmaf(oA1[i], sc0, obuf[0][l][16 + i] * sc1);
                    pk0[rr] = f2bf(v0 * rinv);
                    pk1[rr] = f2bf(v1 * rinv);
                }
                *(u16x4*)(ob + rg * 8) = pk0;
                *(u16x4*)(ob + 32 + rg * 8) = pk1;
            }
        }
        {   // chunk B
            float m1 = mbuf[1][l], ls1 = lsbuf[1][l];
            float mm = fmaxf(mB, m1);
            float sc0 = __builtin_amdgcn_exp2f(mB - mm);
            float sc1 = __builtin_amdgcn_exp2f(m1 - mm);
            float lsm = lsB * sc0 + ls1 * sc1;
            float rs = lsm + __shfl_xor(lsm, 32);
            float rinv = __builtin_amdgcn_rcpf(rs);
            unsigned short* ob = out + ((long)(b * LL + qB)) * DD + h * HD + hi * 4;
#pragma unroll
            for (int rg = 0; rg < 4; ++rg) {
                u16x4 pk0, pk1;
#pragma unroll
                for (int rr = 0; rr < 4; ++rr) {
                    int i = rg * 4 + rr;
                    float v0 = __builtin_fmaf(oB0[i], sc0, obuf[1][l][i] * sc1);
                    float v1 = __builtin_fmaf(oB1[i], sc0, obuf[1][l][16 + i] * sc1);
                    pk0[rr] = f2bf(v0 * rinv);
                    pk1[rr] = f2bf(v1 * rinv);
                }
                *(u16x4*)(ob + rg * 8) = pk0;
                *(u16x4*)(ob + 32 + rg * 8) = pk1;
            }
        }
    }
}

// ---------------------------------------------------------------- launch
extern "C" void kernel_launch(void* const* d_in, const int* in_sizes, int n_in,
                              void* d_out, int out_size, void* d_ws,
                              size_t ws_size, hipStream_t stream) {
    const float* x     = (const float*)d_in[0];
    const int*   mask  = (const int*)d_in[1];
    const int*   qmask = (const int*)d_in[2];
    const float* w_qkv = (const float*)d_in[3];
    const float* w_qkp = (const float*)d_in[4];
    const float* w_fc  = (const float*)d_in[5];
    const float* b_fc  = (const float*)d_in[6];
    const float* shift = (const float*)d_in[7];
    // d_in[8] (bias) cancels in softmax — unused

    char* ws = (char*)d_ws;
    unsigned short* xb   = (unsigned short*)(ws);              //  8 MB bf16 x
    unsigned short* qb   = (unsigned short*)(ws + 8388608);    //  8 MB frag-major Q
    unsigned short* kb   = (unsigned short*)(ws + 16777216);   //  8 MB frag-major K
    unsigned short* vtb  = (unsigned short*)(ws + 25165824);   //  8 MB frag-major V
    unsigned short* qp   = (unsigned short*)(ws + 33554432);   //  1 MB frag-major QP
    unsigned short* kp   = (unsigned short*)(ws + 34603008);   //  1 MB frag-major KP
    unsigned short* wqt  = (unsigned short*)(ws + 35651584);   //  6 MB (3D,D)
    unsigned short* wft  = (unsigned short*)(ws + 41943040);   //  2 MB (D,D)
    unsigned short* aout = (unsigned short*)(ws + 44040192);   //  8 MB (B,L,D)

    prep<<<8704, 256, 0, stream>>>(x, xb, w_qkv, wqt, w_fc, wft, w_qkp, qp, kp);
    gemm8p<<<192, 512, 0, stream>>>(xb, wqt, qb, kb, vtb);
    attn_k<<<1024, 128, 0, stream>>>(qb, kb, vtb, qp, kp, mask, qmask, shift,
                                     aout);
    gemm_fc<<<256, 512, 0, stream>>>(aout, wft, 4096, 1024, 1024, 8,
                                     (float*)d_out, b_fc);
}

// Round 21
// 131.849 us; speedup vs baseline: 1.0690x; 1.0690x over previous
//
#include <hip/hip_runtime.h>
#include <hip/hip_bf16.h>

// B=8, L=512, D=1024, H=16, HD=64
#define BB 8
#define LL 512
#define DD 1024
#define HH 16
#define HD 64
#define LOG2E 1.4426950408889634f

typedef __attribute__((ext_vector_type(8))) unsigned short u16x8;
typedef __attribute__((ext_vector_type(4))) unsigned short u16x4;
typedef __attribute__((ext_vector_type(8))) __bf16 bf16x8;
typedef __attribute__((ext_vector_type(4))) float f32x4;
typedef __attribute__((ext_vector_type(16))) float f32x16;

#define DEV __device__ __forceinline__

DEV unsigned short f2bf(float f) {               // native v_cvt (RNE)
    return __builtin_bit_cast(unsigned short, (__bf16)f);
}
DEV f32x4 mfma16(u16x8 a, u16x8 b, f32x4 c) {
    return __builtin_amdgcn_mfma_f32_16x16x32_bf16(
        __builtin_bit_cast(bf16x8, a), __builtin_bit_cast(bf16x8, b), c, 0, 0, 0);
}
DEV f32x16 mfma32(u16x8 a, u16x8 b, f32x16 c) {
    return __builtin_amdgcn_mfma_f32_32x32x16_bf16(
        __builtin_bit_cast(bf16x8, a), __builtin_bit_cast(bf16x8, b), c, 0, 0, 0);
}
// async global->LDS, 16B per lane; LDS dest = wave-uniform base + lane*16
typedef __attribute__((address_space(1))) void gv_t;
typedef __attribute__((address_space(3))) void lv_t;
DEV void gload16(const void* g, void* l) {
    __builtin_amdgcn_global_load_lds((gv_t*)g, (lv_t*)l, 16, 0, 0);
}

// Frag-major layouts (so every attn load is base + lane*16B, coalesced):
//  Q/K:  X[bh][tile=i>>5][ks=hd>>4][l=hi*32+lq][j]  elem = T[i][hd]
//  QP/KP: same but outer index h
//  V:    V[bh][tile][c=dblk*2+ps][l][j]             elem = V[i][hd]

// --------------------------- fused prep: cvt_x | transpose(wqkv) |
// transpose(wfc) | posg, dispatched by block range (saves 3 kernel gaps)
__global__ __launch_bounds__(256) void prep(
    const float* __restrict__ x, unsigned short* __restrict__ xb,
    const float* __restrict__ w_qkv, unsigned short* __restrict__ wqt,
    const float* __restrict__ w_fc, unsigned short* __restrict__ wft,
    const float* __restrict__ w_qkp, unsigned short* __restrict__ qpx,
    unsigned short* __restrict__ kpx) {
    __shared__ __align__(16) char lds[24576];
    int blk = blockIdx.x;
    int t = threadIdx.x;
    if (blk < 4096) {
        // ---- cvt_x: 1M threads, 4 floats each
        int i = blk * 256 + t;
        f32x4 v = *(const f32x4*)(x + i * 4);
        u16x4 o;
        o[0] = f2bf(v[0]); o[1] = f2bf(v[1]);
        o[2] = f2bf(v[2]); o[3] = f2bf(v[3]);
        *(u16x4*)(xb + i * 4) = o;
    } else if (blk < 7168) {
        // ---- transpose_cvt(w_qkv -> wqt), R=1024, C=3072 (grid 96x32)
        int r = blk - 4096;
        int c0 = (r % 96) * 32, r0 = (r / 96) * 32;
        auto tile = (unsigned short(*)[33])lds;
        int tx = t & 31, ty = t >> 5;
#pragma unroll
        for (int i = 0; i < 32; i += 8)
            tile[ty + i][tx] = f2bf(w_qkv[(r0 + ty + i) * 3072 + c0 + tx]);
        __syncthreads();
#pragma unroll
        for (int i = 0; i < 32; i += 8)
            wqt[(c0 + ty + i) * 1024 + r0 + tx] = tile[tx][ty + i];
    } else if (blk < 8192) {
        // ---- transpose_cvt(w_fc -> wft), R=1024, C=1024 (grid 32x32)
        int r = blk - 7168;
        int c0 = (r % 32) * 32, r0 = (r / 32) * 32;
        auto tile = (unsigned short(*)[33])lds;
        int tx = t & 31, ty = t >> 5;
#pragma unroll
        for (int i = 0; i < 32; i += 8)
            tile[ty + i][tx] = f2bf(w_fc[(r0 + ty + i) * 1024 + c0 + tx]);
        __syncthreads();
#pragma unroll
        for (int i = 0; i < 32; i += 8)
            wft[(c0 + ty + i) * 1024 + r0 + tx] = tile[tx][ty + i];
    } else {
        // ---- posg (grid 64x8): pe(512x64)@w(64x2048) -> frag-major qp|kp
        int r = blk - 8192;
        int c0 = (r % 64) * 32, i0 = (r / 64) * 64;
        auto peS = (float(*)[64])lds;
        auto wS = (float(*)[32])(lds + 16384);
#pragma unroll
        for (int j = 0; j < 16; ++j) {
            int o = t + j * 256;
            int ri = o >> 6, d = o & 63, dd = d & 31;
            float inv = expf((float)dd * -0.2971077539347156f);
            float ang = (float)(i0 + ri - 256) * inv;
            peS[ri][d] = (d < 32) ? sinf(ang) : cosf(ang);
        }
#pragma unroll
        for (int j = 0; j < 8; ++j) {
            int o = t + j * 256;
            wS[o >> 5][o & 31] = w_qkp[(o >> 5) * 2048 + c0 + (o & 31)];
        }
        __syncthreads();
#pragma unroll
        for (int j = 0; j < 8; ++j) {
            int o = t + j * 256;
            int row = o >> 5, col = o & 31;
            float acc = 0.0f;
#pragma unroll
            for (int k = 0; k < 64; ++k) acc += peS[row][k] * wS[k][col];
            int c = c0 + col, i = i0 + row;
            int qt = i >> 5, lq = i & 31;
            int cc = (c < 1024) ? c : (c - 1024);
            int h = cc >> 6, kk = cc & 63;
            int ks = kk >> 4, h2 = (kk >> 3) & 1, jj = kk & 7;
            unsigned idx = ((unsigned)(h * 4096 + qt * 256 + ks * 64 +
                            h2 * 32 + lq) << 3) + jj;
            if (c < 1024) qpx[idx] = f2bf(acc * LOG2E);
            else          kpx[idx] = f2bf(acc);
        }
    }
}

// ---------------------------------------------------------------- GEMM
// C = A(MxK bf16 rm) x Bt(NxK bf16 rm)^T. 128x128 tile, BK=32, 512 threads
// / 8 waves (wave = 64x32 output, acc[4][2]). Triple-buffered LDS (48KB) +
// counted vmcnt (steady 4 = 2 stages in flight) + raw barriers. Bank
// swizzle: LDS[row][c] holds chunk c ^ ((row>>1)&3) via pre-swizzled gload
// SOURCE (dest linear, rule 21) + XOR on ds_read.
// MODE 0: scatter bf16 to frag-major q(*log2e), k, v. MODE 1: fp32 +bias.
template <int MODE>
__global__ __launch_bounds__(512) void gemm_bt(
    const unsigned short* __restrict__ A, const unsigned short* __restrict__ Bt,
    int M, int N, int K, int NBX, unsigned short* __restrict__ o0,
    unsigned short* __restrict__ o1, unsigned short* __restrict__ o2,
    float* __restrict__ fout, const float* __restrict__ bias) {
    __shared__ __align__(16) unsigned short As[3][128 * 32];   // 3 x 8KB
    __shared__ __align__(16) unsigned short Bs[3][128 * 32];
    int g = blockIdx.x;
    int swz = (g & 7) * (gridDim.x >> 3) + (g >> 3);   // XCD-contiguous chunks
    int bx = swz % NBX, by = swz / NBX;
    int m0 = by * 128, n0 = bx * 128;
    int t = threadIdx.x;
    int w = t >> 6, l = t & 63, lg = l >> 4, lc = l & 15;
    int rh = w >> 2, cq = w & 3;            // row-half (64), col-quarter (32)

    f32x4 acc[4][2] = {};

    int sr = t >> 2;                        // staging row 0..127
    int sc = (t & 3) ^ ((t >> 3) & 3);      // swizzled chunk, f(row)=(row>>1)&3
    const unsigned short* Ab = A + (m0 + sr) * K + sc * 8;
    const unsigned short* Bb = Bt + (n0 + sr) * K + sc * 8;
    int rsw = (lc >> 1) & 3;                // read-side f(row)

    auto stage = [&](int buf, int k0) {     // wave w -> rows w*16..w*16+15
        gload16(Ab + k0, &As[buf][w * 512]);
        gload16(Bb + k0, &Bs[buf][w * 512]);
    };

    stage(0, 0);                            // 3-deep prologue (K >= 96)
    stage(1, 32);
    stage(2, 64);
    int cur = 0;
    for (int k0 = 0; k0 < K; k0 += 32) {
        int rem = (K - k0) >> 5;            // tiles left incl. this one
        if (rem > 2)
            asm volatile("s_waitcnt vmcnt(4)" ::: "memory");
        else if (rem == 2)
            asm volatile("s_waitcnt vmcnt(2)" ::: "memory");
        else
            asm volatile("s_waitcnt vmcnt(0)" ::: "memory");
        __builtin_amdgcn_sched_barrier(0);
        __builtin_amdgcn_s_barrier();       // all waves' cur-loads landed
        __builtin_amdgcn_sched_barrier(0);
        u16x8 af[4], bf[2];
#pragma unroll
        for (int mm = 0; mm < 4; ++mm)
            af[mm] = *(const u16x8*)&As[cur][(rh * 64 + mm * 16 + lc) * 32 +
                                             ((lg ^ rsw) << 3)];
#pragma unroll
        for (int nn = 0; nn < 2; ++nn)
            bf[nn] = *(const u16x8*)&Bs[cur][(cq * 32 + nn * 16 + lc) * 32 +
                                             ((lg ^ rsw) << 3)];
        asm volatile("s_waitcnt lgkmcnt(0)" ::: "memory");
        __builtin_amdgcn_sched_barrier(0);
        __builtin_amdgcn_s_barrier();       // all waves done reading cur
        __builtin_amdgcn_sched_barrier(0);
        if (k0 + 96 < K) stage(cur, k0 + 96);   // refill cur with k+3
#pragma unroll
        for (int mm = 0; mm < 4; ++mm)
#pragma unroll
            for (int nn = 0; nn < 2; ++nn)
                acc[mm][nn] = mfma16(af[mm], bf[nn], acc[mm][nn]);
        cur = (cur == 2) ? 0 : cur + 1;
    }

#pragma unroll
    for (int mm = 0; mm < 4; ++mm)
#pragma unroll
        for (int nn = 0; nn < 2; ++nn)
#pragma unroll
            for (int r = 0; r < 4; ++r) {
                int row = m0 + rh * 64 + mm * 16 + lg * 4 + r;
                int col = n0 + cq * 32 + nn * 16 + lc;
                float v = acc[mm][nn][r];
                if (MODE == 0) {
                    int bb = row >> 9, i = row & 511;
                    int which = col >> 10, dd = col & 1023;
                    int hh = dd >> 6, hd = dd & 63;
                    int bh2 = bb * HH + hh;
                    int tl = i >> 5, io = i & 31;
                    if (which == 2) {       // V frag-major
                        int h2 = (io >> 2) & 1, ps = (io >> 4) & 1;
                        int j = (io & 3) | (((io >> 3) & 1) << 2);
                        int dblk = hd >> 5, lq = hd & 31;
                        unsigned idx = ((unsigned)(bh2 * 4096 + tl * 256 +
                                        (dblk * 2 + ps) * 64 + h2 * 32 + lq)
                                        << 3) + j;
                        o2[idx] = f2bf(v);
                    } else {                // Q/K frag-major
                        int ks = hd >> 4, h2 = (hd >> 3) & 1, j = hd & 7;
                        unsigned idx = ((unsigned)(bh2 * 4096 + tl * 256 +
                                        ks * 64 + h2 * 32 + io) << 3) + j;
                        if (which == 0) o0[idx] = f2bf(v * LOG2E);
                        else            o1[idx] = f2bf(v);
                    }
                } else {
                    fout[row * N + col] = v + bias[col];
                }
            }
}

// ---------------------------------------------------------------- attention
// Swapped-QK^T + 2-way key split, frag-major inputs, TWO q-chunks per wave
// (K/KP/V loaded once serve both chunks -> L2 traffic halved; r16-proven).
// __launch_bounds__(256,1): allocator otherwise caps at 64 VGPR for max
// occupancy and spills the ~200-reg state (r13/r14/r15 WRITE blowups).
__global__ __launch_bounds__(256, 1) void attn_k(
    const unsigned short* __restrict__ Qx, const unsigned short* __restrict__ Kx,
    const unsigned short* __restrict__ Vx, const unsigned short* __restrict__ QPx,
    const unsigned short* __restrict__ KPx, const int* __restrict__ mask,
    const int* __restrict__ qmask, const float* __restrict__ shp,
    unsigned short* __restrict__ out) {
    __shared__ float mbuf[2][2][64];
    __shared__ float lsbuf[2][2][64];
    __shared__ float obuf[2][2][64][33];       // +1 pad: conflict-free

    int g = blockIdx.x;                        // 512 blocks
    int bid = ((g & 7) << 6) + (g >> 3);       // one batch per XCD
    int b = bid >> 6, h = (bid >> 2) & 15, qq = bid & 3;
    int t = threadIdx.x, w = t >> 6, l = t & 63;
    int qg = w & 1, kh = w >> 1;               // q-pair-group, key-half
    int lq = l & 31, hi = l >> 5;
    int c0 = qq * 4 + qg * 2;                  // this wave's two q-chunks
    int qA = c0 * 32 + lq, qB = qA + 32;
    int bh = b * HH + h;

    // Q/QP frags for both chunks (chunk B = +256 frags = +2048 elems)
    const unsigned short* qbA  = Qx  + (((unsigned)(bh * 4096 + c0 * 256)) << 3) + (l << 3);
    const unsigned short* qpbA = QPx + (((unsigned)(h  * 4096 + c0 * 256)) << 3) + (l << 3);
    u16x8 qfA[4], pfA[4], qfB[4], pfB[4];
#pragma unroll
    for (int ks = 0; ks < 4; ++ks) {
        qfA[ks] = *(const u16x8*)(qbA + ks * 512);
        pfA[ks] = *(const u16x8*)(qpbA + ks * 512);
        qfB[ks] = *(const u16x8*)(qbA + 2048 + ks * 512);
        pfB[ks] = *(const u16x8*)(qpbA + 2048 + ks * 512);
    }

    // ballot-packed key masks for THIS key half (256 bits, wave-uniform)
    unsigned long long km[4], qm[4];
#pragma unroll
    for (int t8 = 0; t8 < 4; ++t8) {
        int base = b * LL + (kh * 4 + t8) * 64 + l;
        km[t8] = __ballot(mask[base] != 0);
        qm[t8] = __ballot(qmask[base] != 0);
    }
    int qiA = (qmask[b * LL + qA] != 0) ? 1 : 0;
    int qiB = (qmask[b * LL + qB] != 0) ? 1 : 0;

    const float M0 = -1.0e30f, NEGF = -3.0e38f, THR = 8.0f;
    float negs = -(*shp) * LOG2E;
    float mA = M0, lsA = 0.0f, mB = M0, lsB = 0.0f;
    f32x16 oA0 = {}, oA1 = {}, oB0 = {}, oB1 = {};
    float fqA = (float)(qA - 4 * hi);
    float fqB = (float)(qB - 4 * hi);

#pragma unroll
    for (int tt = 0; tt < 8; ++tt) {
        int ttg = kh * 8 + tt;                 // global 32-key tile index
        // ---- K/KP/V frags: loaded ONCE, serve both chunks (coalesced)
        const unsigned short* kb  = Kx  + (((unsigned)(bh * 4096 + ttg * 256)) << 3) + (l << 3);
        const unsigned short* kpb = KPx + (((unsigned)(h  * 4096 + ttg * 256)) << 3) + (l << 3);
        const unsigned short* vb  = Vx  + (((unsigned)(bh * 4096 + ttg * 256)) << 3) + (l << 3);
        u16x8 kf[4], kpf[4], vf[4];
#pragma unroll
        for (int ks = 0; ks < 4; ++ks) {
            kf[ks]  = *(const u16x8*)(kb + ks * 512);
            kpf[ks] = *(const u16x8*)(kpb + ks * 512);
            vf[ks]  = *(const u16x8*)(vb + ks * 512);
        }
        // ---- S^T tiles: two independent chains (A/B interleaved ILP)
        f32x16 sA = {}, sB = {};
#pragma unroll
        for (int ks = 0; ks < 4; ++ks) {
            sA = mfma32(kf[ks], qfA[ks], sA);
            sB = mfma32(kf[ks], qfB[ks], sB);
        }
#pragma unroll
        for (int ks = 0; ks < 4; ++ks) {
            sA = mfma32(kpf[ks], pfA[ks], sA);
            sB = mfma32(kpf[ks], pfB[ks], sB);
        }

        unsigned kwn = ((unsigned)(km[tt >> 1] >> ((tt & 1) * 32))) >> (hi * 4);
        unsigned qwn = ((unsigned)(qm[tt >> 1] >> ((tt & 1) * 32))) >> (hi * 4);
        float btA = fqA - 32.0f * (float)ttg;
        float btB = fqB - 32.0f * (float)ttg;

        // ================= chunk A =================
        {
            float p[16];
#pragma unroll
            for (int r = 0; r < 16; ++r) {
                const int off = (r & 3) + 8 * (r >> 2);
                float v = sA[r];
                v = (((qwn >> off) & 1u) == (unsigned)qiA) ? v : 0.0f;
                float dr = btA - (float)off;
                v = __builtin_fmaf(negs * dr, dr, v);
                v = ((kwn >> off) & 1u) ? v : NEGF;
                p[r] = v;
            }
            float a0 = fmaxf(fmaxf(p[0], p[1]), fmaxf(p[2], p[3]));
            float a1 = fmaxf(fmaxf(p[4], p[5]), fmaxf(p[6], p[7]));
            float a2 = fmaxf(fmaxf(p[8], p[9]), fmaxf(p[10], p[11]));
            float a3 = fmaxf(fmaxf(p[12], p[13]), fmaxf(p[14], p[15]));
            float pmax = fmaxf(fmaxf(a0, a1), fmaxf(a2, a3));
            pmax = fmaxf(pmax, __shfl_xor(pmax, 32));
            if (!__all(pmax <= mA + THR)) {
                float mn = fmaxf(mA, pmax);
                float sc = __builtin_amdgcn_exp2f(mA - mn);
#pragma unroll
                for (int r = 0; r < 16; ++r) { oA0[r] *= sc; oA1[r] *= sc; }
                lsA *= sc;
                mA = mn;
            }
#pragma unroll
            for (int r = 0; r < 16; ++r) p[r] = __builtin_amdgcn_exp2f(p[r] - mA);
            lsA += (((p[0] + p[1]) + (p[2] + p[3])) + ((p[4] + p[5]) + (p[6] + p[7]))) +
                   (((p[8] + p[9]) + (p[10] + p[11])) +
                    ((p[12] + p[13]) + (p[14] + p[15])));
            u16x8 pf0, pf1;
#pragma unroll
            for (int j = 0; j < 8; ++j) { pf0[j] = f2bf(p[j]); pf1[j] = f2bf(p[8 + j]); }
            oA0 = mfma32(vf[0], pf0, oA0);
            oA0 = mfma32(vf[1], pf1, oA0);
            oA1 = mfma32(vf[2], pf0, oA1);
            oA1 = mfma32(vf[3], pf1, oA1);
        }
        // ================= chunk B =================
        {
            float p[16];
#pragma unroll
            for (int r = 0; r < 16; ++r) {
                const int off = (r & 3) + 8 * (r >> 2);
                float v = sB[r];
                v = (((qwn >> off) & 1u) == (unsigned)qiB) ? v : 0.0f;
                float dr = btB - (float)off;
                v = __builtin_fmaf(negs * dr, dr, v);
                v = ((kwn >> off) & 1u) ? v : NEGF;
                p[r] = v;
            }
            float a0 = fmaxf(fmaxf(p[0], p[1]), fmaxf(p[2], p[3]));
            float a1 = fmaxf(fmaxf(p[4], p[5]), fmaxf(p[6], p[7]));
            float a2 = fmaxf(fmaxf(p[8], p[9]), fmaxf(p[10], p[11]));
            float a3 = fmaxf(fmaxf(p[12], p[13]), fmaxf(p[14], p[15]));
            float pmax = fmaxf(fmaxf(a0, a1), fmaxf(a2, a3));
            pmax = fmaxf(pmax, __shfl_xor(pmax, 32));
            if (!__all(pmax <= mB + THR)) {
                float mn = fmaxf(mB, pmax);
                float sc = __builtin_amdgcn_exp2f(mB - mn);
#pragma unroll
                for (int r = 0; r < 16; ++r) { oB0[r] *= sc; oB1[r] *= sc; }
                lsB *= sc;
                mB = mn;
            }
#pragma unroll
            for (int r = 0; r < 16; ++r) p[r] = __builtin_amdgcn_exp2f(p[r] - mB);
            lsB += (((p[0] + p[1]) + (p[2] + p[3])) + ((p[4] + p[5]) + (p[6] + p[7]))) +
                   (((p[8] + p[9]) + (p[10] + p[11])) +
                    ((p[12] + p[13]) + (p[14] + p[15])));
            u16x8 pf0, pf1;
#pragma unroll
            for (int j = 0; j < 8; ++j) { pf0[j] = f2bf(p[j]); pf1[j] = f2bf(p[8 + j]); }
            oB0 = mfma32(vf[0], pf0, oB0);
            oB0 = mfma32(vf[1], pf1, oB0);
            oB1 = mfma32(vf[2], pf0, oB1);
            oB1 = mfma32(vf[3], pf1, oB1);
        }
    }

    // ---- flash-combine the two key halves via LDS (both chunks)
    if (kh == 1) {
        mbuf[qg][0][l] = mA;  lsbuf[qg][0][l] = lsA;
        mbuf[qg][1][l] = mB;  lsbuf[qg][1][l] = lsB;
#pragma unroll
        for (int r = 0; r < 16; ++r) {
            obuf[qg][0][l][r] = oA0[r];
            obuf[qg][0][l][16 + r] = oA1[r];
            obuf[qg][1][l][r] = oB0[r];
            obuf[qg][1][l][16 + r] = oB1[r];
        }
    }
    __syncthreads();
    if (kh == 0) {
        // ---- chunk A
        {
            float m1 = mbuf[qg][0][l], ls1 = lsbuf[qg][0][l];
            float mm = fmaxf(mA, m1);
            float sc0 = __builtin_amdgcn_exp2f(mA - mm);
            float sc1 = __builtin_amdgcn_exp2f(m1 - mm);
            float lsm = lsA * sc0 + ls1 * sc1;
            float rs = lsm + __shfl_xor(lsm, 32);
            float rinv = __builtin_amdgcn_rcpf(rs);
            unsigned short* ob = out + ((long)(b * LL + qA)) * DD + h * HD + hi * 4;
#pragma unroll
            for (int rg = 0; rg < 4; ++rg) {
                u16x4 pk0, pk1;
#pragma unroll
                for (int rr = 0; rr < 4; ++rr) {
                    int i = rg * 4 + rr;
                    float v0 = __builtin_fmaf(oA0[i], sc0, obuf[qg][0][l][i] * sc1);
                    float v1 = __builtin_fmaf(oA1[i], sc0, obuf[qg][0][l][16 + i] * sc1);
                    pk0[rr] = f2bf(v0 * rinv);
                    pk1[rr] = f2bf(v1 * rinv);
                }
                *(u16x4*)(ob + rg * 8) = pk0;
                *(u16x4*)(ob + 32 + rg * 8) = pk1;
            }
        }
        // ---- chunk B
        {
            float m1 = mbuf[qg][1][l], ls1 = lsbuf[qg][1][l];
            float mm = fmaxf(mB, m1);
            float sc0 = __builtin_amdgcn_exp2f(mB - mm);
            float sc1 = __builtin_amdgcn_exp2f(m1 - mm);
            float lsm = lsB * sc0 + ls1 * sc1;
            float rs = lsm + __shfl_xor(lsm, 32);
            float rinv = __builtin_amdgcn_rcpf(rs);
            unsigned short* ob = out + ((long)(b * LL + qB)) * DD + h * HD + hi * 4;
#pragma unroll
            for (int rg = 0; rg < 4; ++rg) {
                u16x4 pk0, pk1;
#pragma unroll
                for (int rr = 0; rr < 4; ++rr) {
                    int i = rg * 4 + rr;
                    float v0 = __builtin_fmaf(oB0[i], sc0, obuf[qg][1][l][i] * sc1);
                    float v1 = __builtin_fmaf(oB1[i], sc0, obuf[qg][1][l][16 + i] * sc1);
                    pk0[rr] = f2bf(v0 * rinv);
                    pk1[rr] = f2bf(v1 * rinv);
                }
                *(u16x4*)(ob + rg * 8) = pk0;
                *(u16x4*)(ob + 32 + rg * 8) = pk1;
            }
        }
    }
}

// ---------------------------------------------------------------- launch
extern "C" void kernel_launch(void* const* d_in, const int* in_sizes, int n_in,
                              void* d_out, int out_size, void* d_ws,
                              size_t ws_size, hipStream_t stream) {
    const float* x     = (const float*)d_in[0];
    const int*   mask  = (const int*)d_in[1];
    const int*   qmask = (const int*)d_in[2];
    const float* w_qkv = (const float*)d_in[3];
    const float* w_qkp = (const float*)d_in[4];
    const float* w_fc  = (const float*)d_in[5];
    const float* b_fc  = (const float*)d_in[6];
    const float* shift = (const float*)d_in[7];
    // d_in[8] (bias) cancels in softmax — unused

    char* ws = (char*)d_ws;
    unsigned short* xb   = (unsigned short*)(ws);              //  8 MB bf16 x
    unsigned short* qb   = (unsigned short*)(ws + 8388608);    //  8 MB frag-major Q
    unsigned short* kb   = (unsigned short*)(ws + 16777216);   //  8 MB frag-major K
    unsigned short* vtb  = (unsigned short*)(ws + 25165824);   //  8 MB frag-major V
    unsigned short* qp   = (unsigned short*)(ws + 33554432);   //  1 MB frag-major QP
    unsigned short* kp   = (unsigned short*)(ws + 34603008);   //  1 MB frag-major KP
    unsigned short* wqt  = (unsigned short*)(ws + 35651584);   //  6 MB (3D,D)
    unsigned short* wft  = (unsigned short*)(ws + 41943040);   //  2 MB (D,D)
    unsigned short* aout = (unsigned short*)(ws + 44040192);   //  8 MB (B,L,D)

    prep<<<8704, 256, 0, stream>>>(x, xb, w_qkv, wqt, w_fc, wft, w_qkp, qp, kp);
    gemm_bt<0><<<768, 512, 0, stream>>>(xb, wqt, 4096, 3072, 1024, 24, qb, kb,
                                        vtb, nullptr, nullptr);
    attn_k<<<512, 256, 0, stream>>>(qb, kb, vtb, qp, kp, mask, qmask, shift,
                                    aout);
    gemm_bt<1><<<256, 512, 0, stream>>>(aout, wft, 4096, 1024, 1024, 8, nullptr,
                                        nullptr, nullptr, (float*)d_out, b_fc);
}